// Round 1
// baseline (875.517 us; speedup 1.0000x reference)
//
#include <hip/hip_runtime.h>

#define DEV __device__ __forceinline__

typedef unsigned short u16;
typedef __bf16 bf16x8 __attribute__((ext_vector_type(8)));
typedef bf16x8 __attribute__((may_alias)) bf16x8a;
typedef float f32x4 __attribute__((ext_vector_type(4)));

constexpr int NB = 4, NS = 2048, NE = 1024, NH = 4, NDH = 256, NF = 4096;
constexpr int NR = NB * NS;  // 8192 rows

DEV u16 f2bf(float f) {
  unsigned u = __float_as_uint(f);
  u += 0x7fff + ((u >> 16) & 1);
  return (u16)(u >> 16);
}

DEV f32x4 mfma16(bf16x8 a, bf16x8 b, f32x4 c) {
  return __builtin_amdgcn_mfma_f32_16x16x32_bf16(a, b, c, 0, 0, 0);
}

DEV bf16x8 ldfrag(const u16* p) { return *(const bf16x8a*)p; }

DEV void gload_lds16(const void* g, void* l) {
  __builtin_amdgcn_global_load_lds(
      (const __attribute__((address_space(1))) void*)g,
      (__attribute__((address_space(3))) void*)l, 16, 0, 0);
}

// ---------------- elementwise cast f32 -> bf16 ----------------
__global__ void cast_f32_bf16(const float* __restrict__ in, u16* __restrict__ out, int n4) {
  int i = blockIdx.x * 256 + threadIdx.x;
  if (i >= n4) return;
  float4 v = ((const float4*)in)[i];
  ushort4 o;
  o.x = f2bf(v.x); o.y = f2bf(v.y); o.z = f2bf(v.z); o.w = f2bf(v.w);
  ((ushort4*)out)[i] = o;
}

// ---------------- batched transpose + cast: in[z][R][C] f32 -> out[z][C][R] bf16 ----------------
__global__ void transpose_cast(const float* __restrict__ in, u16* __restrict__ out, int R, int C) {
  __shared__ float t[32][33];
  size_t base = (size_t)blockIdx.z * R * C;
  int c0 = blockIdx.x * 32, r0 = blockIdx.y * 32;
  int x = threadIdx.x;
  for (int yy = threadIdx.y; yy < 32; yy += 8)
    t[yy][x] = in[base + (size_t)(r0 + yy) * C + c0 + x];
  __syncthreads();
  for (int yy = threadIdx.y; yy < 32; yy += 8)
    out[base + (size_t)(c0 + yy) * R + r0 + x] = f2bf(t[x][yy]);
}

// ---------------- V transpose: V[(b*S+s)*vstride + h*DH + d] -> Vt[(bh*DH+d)*S + s] ----------------
__global__ void transpose_v(const u16* __restrict__ V, int vstride, u16* __restrict__ Vt) {
  __shared__ u16 t[32][34];
  int bh = blockIdx.z, b = bh >> 2, h = bh & (NH - 1);
  int s0 = blockIdx.x * 32, d0 = blockIdx.y * 32;
  int x = threadIdx.x;
  for (int yy = threadIdx.y; yy < 32; yy += 8)
    t[yy][x] = V[(size_t)(b * NS + s0 + yy) * vstride + h * NDH + d0 + x];
  __syncthreads();
  for (int yy = threadIdx.y; yy < 32; yy += 8)
    Vt[((size_t)bh * NDH + d0 + yy) * NS + s0 + x] = t[x][yy];
}

// ---------------- small f32 copy (bias packing) ----------------
__global__ void copy_f32(const float* __restrict__ s, float* __restrict__ d, int n) {
  int i = blockIdx.x * 256 + threadIdx.x;
  if (i < n) d[i] = s[i];
}

// ---------------- GEMM: C[M,N] = A[M,K](bf16) * Bt[N,K]^T(bf16) (+bias, +res, relu) ----------------
// 128x128 tile, 4 waves (2x2), 4x4 16x16x32 frags per wave, BK=32, global_load_lds staging.
template<int OUTF32, int RELU>
__global__ __launch_bounds__(256, 2)
void gemm_bt(const u16* __restrict__ A, const u16* __restrict__ Bt,
             const float* __restrict__ bias, const float* __restrict__ res,
             float* __restrict__ outF, u16* __restrict__ outB,
             int M, int N, int K)
{
  __shared__ u16 lA[128 * 32];
  __shared__ u16 lB[128 * 32];
  int tid = threadIdx.x;
  int wid = tid >> 6, lane = tid & 63;
  int lr = lane & 15, lk = lane >> 4;
  int wm = wid >> 1, wn = wid & 1;
  int rowBlk = blockIdx.y * 128, colBlk = blockIdx.x * 128;

  f32x4 acc[4][4];
#pragma unroll
  for (int i = 0; i < 4; i++)
#pragma unroll
    for (int j = 0; j < 4; j++) acc[i][j] = (f32x4){0.f, 0.f, 0.f, 0.f};

  const u16* gA = A + (size_t)(rowBlk + wid * 32 + (lane >> 2)) * K + (lane & 3) * 8;
  const u16* gB = Bt + (size_t)(colBlk + wid * 32 + (lane >> 2)) * K + (lane & 3) * 8;
  u16* lAw = lA + wid * 1024;
  u16* lBw = lB + wid * 1024;

  for (int kk = 0; kk < K; kk += 32) {
    __syncthreads();
    gload_lds16(gA + kk, lAw);
    gload_lds16(gA + kk + (size_t)16 * K, lAw + 512);
    gload_lds16(gB + kk, lBw);
    gload_lds16(gB + kk + (size_t)16 * K, lBw + 512);
    asm volatile("s_waitcnt vmcnt(0)" ::: "memory");
    __syncthreads();

    bf16x8 af[4], bf[4];
#pragma unroll
    for (int fm = 0; fm < 4; fm++)
      af[fm] = ldfrag(lA + (wm * 64 + fm * 16 + lr) * 32 + lk * 8);
#pragma unroll
    for (int fn = 0; fn < 4; fn++)
      bf[fn] = ldfrag(lB + (wn * 64 + fn * 16 + lr) * 32 + lk * 8);
#pragma unroll
    for (int fm = 0; fm < 4; fm++)
#pragma unroll
      for (int fn = 0; fn < 4; fn++)
        acc[fm][fn] = mfma16(af[fm], bf[fn], acc[fm][fn]);
  }

  int orow = rowBlk + wm * 64;
  int ocol = colBlk + wn * 64;
#pragma unroll
  for (int fn = 0; fn < 4; fn++) {
    int c = ocol + fn * 16 + lr;
    float bv = bias[c];
#pragma unroll
    for (int fm = 0; fm < 4; fm++) {
      int r0 = orow + fm * 16 + lk * 4;
#pragma unroll
      for (int j = 0; j < 4; j++) {
        float v = acc[fm][fn][j] + bv;
        if (OUTF32) v += res[(size_t)(r0 + j) * N + c];
        if (RELU) v = fmaxf(v, 0.f);
        if (OUTF32) outF[(size_t)(r0 + j) * N + c] = v;
        else        outB[(size_t)(r0 + j) * N + c] = f2bf(v);
      }
    }
  }
}

// ---------------- flash attention ----------------
// grid 512 = 16 bh * 32 qtiles; 4 waves, each wave: 16 q-rows x DH=256.
// K-tile LDS [32][256] with XOR slot swizzle; V staged from Vt as [g=4][d=256][8].
template<int CAUSAL>
__global__ __launch_bounds__(256, 2)
void attn_kernel(const u16* __restrict__ Qp, int qstride,
                 const u16* __restrict__ Kp, int kstride,
                 const u16* __restrict__ Vt, u16* __restrict__ O)
{
  int bidx = blockIdx.x;
  int bh = bidx & (NB * NH - 1);
  int qt = (NS / 64 - 1) - (bidx >> 4);
  int b = bh >> 2, h = bh & (NH - 1);
  int tid = threadIdx.x, wid = tid >> 6, lane = tid & 63;
  int lr = lane & 15, lk = lane >> 4;

  __shared__ u16 lK[32 * 256];
  __shared__ u16 lV[4 * 256 * 8];
  __shared__ u16 lP[4][16 * 32];

  const u16* qbase = Qp + (size_t)(b * NS + qt * 64 + wid * 16 + lr) * qstride + h * NDH;
  bf16x8 qf[8];
#pragma unroll
  for (int k8 = 0; k8 < 8; k8++) qf[k8] = ldfrag(qbase + k8 * 32 + lk * 8);

  f32x4 oacc[16];
#pragma unroll
  for (int dc = 0; dc < 16; dc++) oacc[dc] = (f32x4){0.f, 0.f, 0.f, 0.f};
  float m[4] = {-1e30f, -1e30f, -1e30f, -1e30f};
  float l[4] = {0.f, 0.f, 0.f, 0.f};

  int nkt = CAUSAL ? (2 * qt + 2) : (NS / 32);
  constexpr float SC = 1.0f / NDH;

  for (int kt = 0; kt < nkt; kt++) {
    __syncthreads();
#pragma unroll
    for (int i = 0; i < 4; i++) {
      int cc = wid * 4 + i;
      int krow = 2 * cc + (lane >> 5);
      int kslot = (lane & 31) ^ (krow & 7);
      gload_lds16(Kp + (size_t)(b * NS + kt * 32 + krow) * kstride + h * NDH + kslot * 8,
                  lK + cc * 512);
      int u = cc * 64 + lane;
      int vg = u >> 8, vd = u & 255;
      gload_lds16(Vt + ((size_t)bh * NDH + vd) * NS + kt * 32 + vg * 8,
                  lV + cc * 512);
    }
    asm volatile("s_waitcnt vmcnt(0)" ::: "memory");
    __syncthreads();

    // QK^T
    f32x4 sf0 = (f32x4){0.f, 0.f, 0.f, 0.f};
    f32x4 sf1 = (f32x4){0.f, 0.f, 0.f, 0.f};
#pragma unroll
    for (int k8 = 0; k8 < 8; k8++) {
      int ps = ((k8 * 4 + lk) ^ (lr & 7)) * 8;
      bf16x8 kf0 = ldfrag(lK + lr * 256 + ps);
      bf16x8 kf1 = ldfrag(lK + (16 + lr) * 256 + ps);
      sf0 = mfma16(qf[k8], kf0, sf0);
      sf1 = mfma16(qf[k8], kf1, sf1);
    }

    // online softmax (rows live in regs j, cols across 16 lanes of same lk group)
    float tmax[4];
#pragma unroll
    for (int j = 0; j < 4; j++) {
      float a0 = sf0[j] * SC, a1 = sf1[j] * SC;
      if (CAUSAL) {
        int q = qt * 64 + wid * 16 + lk * 4 + j;
        if (kt * 32 + lr > q)      a0 = -1e30f;
        if (kt * 32 + 16 + lr > q) a1 = -1e30f;
      }
      sf0[j] = a0; sf1[j] = a1;
      tmax[j] = fmaxf(a0, a1);
    }
#pragma unroll
    for (int j = 0; j < 4; j++) {
      tmax[j] = fmaxf(tmax[j], __shfl_xor(tmax[j], 1));
      tmax[j] = fmaxf(tmax[j], __shfl_xor(tmax[j], 2));
      tmax[j] = fmaxf(tmax[j], __shfl_xor(tmax[j], 4));
      tmax[j] = fmaxf(tmax[j], __shfl_xor(tmax[j], 8));
    }
    float resc[4], psum[4];
    u16* myP = &lP[wid][0];
#pragma unroll
    for (int j = 0; j < 4; j++) {
      float mn = fmaxf(m[j], tmax[j]);
      resc[j] = __expf(m[j] - mn);
      m[j] = mn;
      float p0 = __expf(sf0[j] - mn);
      float p1 = __expf(sf1[j] - mn);
      psum[j] = p0 + p1;
      myP[(lk * 4 + j) * 32 + lr]      = f2bf(p0);
      myP[(lk * 4 + j) * 32 + 16 + lr] = f2bf(p1);
    }
#pragma unroll
    for (int j = 0; j < 4; j++) {
      psum[j] += __shfl_xor(psum[j], 1);
      psum[j] += __shfl_xor(psum[j], 2);
      psum[j] += __shfl_xor(psum[j], 4);
      psum[j] += __shfl_xor(psum[j], 8);
      l[j] = l[j] * resc[j] + psum[j];
    }
#pragma unroll
    for (int dc = 0; dc < 16; dc++) {
      f32x4 t = oacc[dc];
      t[0] *= resc[0]; t[1] *= resc[1]; t[2] *= resc[2]; t[3] *= resc[3];
      oacc[dc] = t;
    }
    asm volatile("s_waitcnt lgkmcnt(0)" ::: "memory");
    bf16x8 pf = ldfrag(myP + lr * 32 + lk * 8);
#pragma unroll
    for (int dc = 0; dc < 16; dc++) {
      bf16x8 vf = ldfrag(lV + lk * 2048 + (dc * 16 + lr) * 8);
      oacc[dc] = mfma16(pf, vf, oacc[dc]);
    }
  }

  float inv[4];
#pragma unroll
  for (int j = 0; j < 4; j++) inv[j] = 1.f / l[j];
#pragma unroll
  for (int dc = 0; dc < 16; dc++) {
#pragma unroll
    for (int j = 0; j < 4; j++) {
      size_t row = (size_t)(b * NS + qt * 64 + wid * 16 + lk * 4 + j);
      O[row * NE + h * NDH + dc * 16 + lr] = f2bf(oacc[dc][j] * inv[j]);
    }
  }
}

// ---------------- LayerNorm (eps=1e-3), optional relu, optional bf16 copy ----------------
template<int RELU, int WBF>
__global__ __launch_bounds__(256)
void ln_kernel(const float* __restrict__ x, const float* __restrict__ g,
               const float* __restrict__ bb, float* __restrict__ outF,
               u16* __restrict__ outB)
{
  int row = blockIdx.x, tid = threadIdx.x;
  float4 v = ((const float4*)(x + (size_t)row * NE))[tid];
  float s = v.x + v.y + v.z + v.w;
  float s2 = v.x * v.x + v.y * v.y + v.z * v.z + v.w * v.w;
#pragma unroll
  for (int off = 32; off; off >>= 1) {
    s += __shfl_xor(s, off);
    s2 += __shfl_xor(s2, off);
  }
  __shared__ float red[8];
  int wid = tid >> 6, lane = tid & 63;
  if (lane == 0) { red[wid] = s; red[4 + wid] = s2; }
  __syncthreads();
  s = red[0] + red[1] + red[2] + red[3];
  s2 = red[4] + red[5] + red[6] + red[7];
  float mean = s * (1.f / NE);
  float var = s2 * (1.f / NE) - mean * mean;
  float rstd = rsqrtf(var + 1e-3f);
  float4 gg = ((const float4*)g)[tid];
  float4 bv = ((const float4*)bb)[tid];
  float4 o;
  o.x = (v.x - mean) * rstd * gg.x + bv.x;
  o.y = (v.y - mean) * rstd * gg.y + bv.y;
  o.z = (v.z - mean) * rstd * gg.z + bv.z;
  o.w = (v.w - mean) * rstd * gg.w + bv.w;
  if (RELU) {
    o.x = fmaxf(o.x, 0.f); o.y = fmaxf(o.y, 0.f);
    o.z = fmaxf(o.z, 0.f); o.w = fmaxf(o.w, 0.f);
  }
  ((float4*)(outF + (size_t)row * NE))[tid] = o;
  if (WBF) {
    ushort4 ob;
    ob.x = f2bf(o.x); ob.y = f2bf(o.y); ob.z = f2bf(o.z); ob.w = f2bf(o.w);
    ((ushort4*)(outB + (size_t)row * NE))[tid] = ob;
  }
}

// ---------------- workspace layout (bytes) ----------------
constexpr size_t OFF_X    = 0;                       // 16 MB: Xbf -> O1 -> Ctxbf -> O2
constexpr size_t OFF_W    = OFF_X + 16777216;        // 32 MB packed weights
constexpr size_t OFF_BIAS = OFF_W + 33554432;        // packed biases
constexpr size_t OFF_QKV  = OFF_BIAS + 32768;        // 48 MB QKV1 / (KV2 + Q2) / MID(64MB spans into VT)
constexpr size_t OFF_VT   = OFF_QKV + 50331648;      // 16 MB Vt
constexpr size_t OFF_T0   = OFF_VT + 16777216;       // 32 MB f32 scratch (pre-LN)
constexpr size_t OFF_A    = OFF_T0 + 33554432;       // 32 MB f32 a / c
constexpr size_t OFF_ABF  = OFF_A + 33554432;        // 16 MB bf16 a / c

extern "C" void kernel_launch(void* const* d_in, const int* in_sizes, int n_in,
                              void* d_out, int out_size, void* d_ws, size_t ws_size,
                              hipStream_t stream) {
  (void)in_sizes; (void)n_in; (void)out_size; (void)ws_size;
  const float* inp = (const float*)d_in[0];
  const float* ctx = (const float*)d_in[1];
  const float* Wk1 = (const float*)d_in[2];  const float* bk1 = (const float*)d_in[3];
  const float* Wq1 = (const float*)d_in[4];  const float* bq1 = (const float*)d_in[5];
  const float* Wv1 = (const float*)d_in[6];  const float* bv1 = (const float*)d_in[7];
  const float* Wo1 = (const float*)d_in[8];  const float* bo1 = (const float*)d_in[9];
  const float* Wk2 = (const float*)d_in[10]; const float* bk2 = (const float*)d_in[11];
  const float* Wq2 = (const float*)d_in[12]; const float* bq2 = (const float*)d_in[13];
  const float* Wv2 = (const float*)d_in[14]; const float* bv2 = (const float*)d_in[15];
  const float* Wo2 = (const float*)d_in[16]; const float* bo2 = (const float*)d_in[17];
  const float* lng = (const float*)d_in[18]; const float* lnb = (const float*)d_in[19];
  const float* W1  = (const float*)d_in[20]; const float* b1  = (const float*)d_in[21];
  const float* W2  = (const float*)d_in[22]; const float* b2  = (const float*)d_in[23];
  float* out = (float*)d_out;
  char* ws = (char*)d_ws;

  u16* XBF    = (u16*)(ws + OFF_X);        // also ctx-bf16 and attention-O buffer
  u16* WQKV1T = (u16*)(ws + OFF_W);        // rows [K|Q|V] x 1024
  u16* WKV2T  = WQKV1T + 3072 * 1024;      // rows [K|V] x 1024
  u16* WQ2T   = WKV2T + 2048 * 1024;
  u16* WO1T   = WQ2T + 1024 * 1024;
  u16* WO2T   = WO1T + 1024 * 1024;
  u16* W1T    = WO2T + 1024 * 1024;        // [4096][1024]
  u16* W2T    = W1T + 4096 * 1024;         // [1024][4096]
  float* BQKV1 = (float*)(ws + OFF_BIAS);  // 3072
  float* BKV2  = BQKV1 + 3072;             // 2048
  u16* QKV  = (u16*)(ws + OFF_QKV);        // [8192][3072] (self) / [8192][2048] KV2
  u16* Q2   = QKV + 8192 * 2048;           // [8192][1024]
  u16* VT   = (u16*)(ws + OFF_VT);         // [16][256][2048]
  u16* MID  = QKV;                         // [8192][4096] (aliases QKV+VT, both dead)
  float* T0 = (float*)(ws + OFF_T0);
  float* Af = (float*)(ws + OFF_A);
  u16* ABF  = (u16*)(ws + OFF_ABF);
  u16* Obuf = XBF;

  dim3 tb(32, 8);

  // input cast + weight/bias packing
  cast_f32_bf16<<<8192, 256, 0, stream>>>(inp, XBF, NR * NE / 4);
  transpose_cast<<<dim3(8, 32, 4), tb, 0, stream>>>(Wk1, WQKV1T,               NE, NDH);
  transpose_cast<<<dim3(8, 32, 4), tb, 0, stream>>>(Wq1, WQKV1T + 1024 * 1024, NE, NDH);
  transpose_cast<<<dim3(8, 32, 4), tb, 0, stream>>>(Wv1, WQKV1T + 2048 * 1024, NE, NDH);
  transpose_cast<<<dim3(32, 32, 1), tb, 0, stream>>>(Wo1, WO1T, NE, NE);
  transpose_cast<<<dim3(8, 32, 4), tb, 0, stream>>>(Wk2, WKV2T,               NE, NDH);
  transpose_cast<<<dim3(8, 32, 4), tb, 0, stream>>>(Wv2, WKV2T + 1024 * 1024, NE, NDH);
  transpose_cast<<<dim3(8, 32, 4), tb, 0, stream>>>(Wq2, WQ2T, NE, NDH);
  transpose_cast<<<dim3(32, 32, 1), tb, 0, stream>>>(Wo2, WO2T, NE, NE);
  transpose_cast<<<dim3(128, 32, 1), tb, 0, stream>>>(W1, W1T, NE, NF);
  transpose_cast<<<dim3(32, 128, 1), tb, 0, stream>>>(W2, W2T, NF, NE);
  copy_f32<<<4, 256, 0, stream>>>(bk1, BQKV1, 1024);
  copy_f32<<<4, 256, 0, stream>>>(bq1, BQKV1 + 1024, 1024);
  copy_f32<<<4, 256, 0, stream>>>(bv1, BQKV1 + 2048, 1024);
  copy_f32<<<4, 256, 0, stream>>>(bk2, BKV2, 1024);
  copy_f32<<<4, 256, 0, stream>>>(bv2, BKV2 + 1024, 1024);

  // ---- self-attention block ----
  gemm_bt<0, 0><<<dim3(24, 64), 256, 0, stream>>>(XBF, WQKV1T, BQKV1, nullptr,
                                                  nullptr, QKV, NR, 3072, NE);
  transpose_v<<<dim3(64, 8, 16), tb, 0, stream>>>(QKV + 2048, 3072, VT);
  attn_kernel<1><<<512, 256, 0, stream>>>(QKV + 1024, 3072, QKV, 3072, VT, Obuf);
  gemm_bt<1, 0><<<dim3(8, 64), 256, 0, stream>>>(Obuf, WO1T, bo1, inp,
                                                 T0, nullptr, NR, NE, NE);
  ln_kernel<0, 1><<<NR, 256, 0, stream>>>(T0, lng, lnb, Af, ABF);

  // ---- cross-attention block ----
  cast_f32_bf16<<<8192, 256, 0, stream>>>(ctx, XBF, NR * NE / 4);
  gemm_bt<0, 0><<<dim3(16, 64), 256, 0, stream>>>(XBF, WKV2T, BKV2, nullptr,
                                                  nullptr, QKV, NR, 2048, NE);
  gemm_bt<0, 0><<<dim3(8, 64), 256, 0, stream>>>(ABF, WQ2T, bq2, nullptr,
                                                 nullptr, Q2, NR, NE, NE);
  transpose_v<<<dim3(64, 8, 16), tb, 0, stream>>>(QKV + 1024, 2048, VT);
  attn_kernel<0><<<512, 256, 0, stream>>>(Q2, 1024, QKV, 2048, VT, Obuf);
  gemm_bt<1, 0><<<dim3(8, 64), 256, 0, stream>>>(Obuf, WO2T, bo2, Af,
                                                 T0, nullptr, NR, NE, NE);
  ln_kernel<0, 1><<<NR, 256, 0, stream>>>(T0, lng, lnb, Af, ABF);

  // ---- FFN ----
  gemm_bt<0, 1><<<dim3(32, 64), 256, 0, stream>>>(ABF, W1T, b1, nullptr,
                                                  nullptr, MID, NR, NF, NE);
  gemm_bt<1, 0><<<dim3(8, 64), 256, 0, stream>>>(MID, W2T, b2, Af,
                                                 T0, nullptr, NR, NE, NF);
  ln_kernel<1, 0><<<NR, 256, 0, stream>>>(T0, lng, lnb, out, nullptr);
}

// Round 2
// 865.776 us; speedup vs baseline: 1.0113x; 1.0113x over previous
//
#include <hip/hip_runtime.h>

#define DEV __device__ __forceinline__

typedef unsigned short u16;
typedef __bf16 bf16x8 __attribute__((ext_vector_type(8)));
typedef bf16x8 __attribute__((may_alias)) bf16x8a;
typedef float f32x4 __attribute__((ext_vector_type(4)));

constexpr int NB = 4, NS = 2048, NE = 1024, NH = 4, NDH = 256, NF = 4096;
constexpr int NR = NB * NS;  // 8192 rows

DEV u16 f2bf(float f) {
  unsigned u = __float_as_uint(f);
  u += 0x7fff + ((u >> 16) & 1);
  return (u16)(u >> 16);
}

DEV f32x4 mfma16(bf16x8 a, bf16x8 b, f32x4 c) {
  return __builtin_amdgcn_mfma_f32_16x16x32_bf16(a, b, c, 0, 0, 0);
}

DEV bf16x8 ldfrag(const u16* p) { return *(const bf16x8a*)p; }

DEV void gload_lds16(const void* g, void* l) {
  __builtin_amdgcn_global_load_lds(
      (const __attribute__((address_space(1))) void*)g,
      (__attribute__((address_space(3))) void*)l, 16, 0, 0);
}

// ---------------- elementwise cast f32 -> bf16 ----------------
__global__ void cast_f32_bf16(const float* __restrict__ in, u16* __restrict__ out, int n4) {
  int i = blockIdx.x * 256 + threadIdx.x;
  if (i >= n4) return;
  float4 v = ((const float4*)in)[i];
  ushort4 o;
  o.x = f2bf(v.x); o.y = f2bf(v.y); o.z = f2bf(v.z); o.w = f2bf(v.w);
  ((ushort4*)out)[i] = o;
}

// ---------------- batched transpose + cast: in[z][R][C] f32 -> out[z][C][R] bf16 ----------------
__global__ void transpose_cast(const float* __restrict__ in, u16* __restrict__ out, int R, int C) {
  __shared__ float t[32][33];
  size_t base = (size_t)blockIdx.z * R * C;
  int c0 = blockIdx.x * 32, r0 = blockIdx.y * 32;
  int x = threadIdx.x;
  for (int yy = threadIdx.y; yy < 32; yy += 8)
    t[yy][x] = in[base + (size_t)(r0 + yy) * C + c0 + x];
  __syncthreads();
  for (int yy = threadIdx.y; yy < 32; yy += 8)
    out[base + (size_t)(c0 + yy) * R + r0 + x] = f2bf(t[x][yy]);
}

// ---------------- V transpose: V[(b*S+s)*vstride + h*DH + d] -> Vt[(bh*DH+d)*S + s] ----------------
__global__ void transpose_v(const u16* __restrict__ V, int vstride, u16* __restrict__ Vt) {
  __shared__ u16 t[32][34];
  int bh = blockIdx.z, b = bh >> 2, h = bh & (NH - 1);
  int s0 = blockIdx.x * 32, d0 = blockIdx.y * 32;
  int x = threadIdx.x;
  for (int yy = threadIdx.y; yy < 32; yy += 8)
    t[yy][x] = V[(size_t)(b * NS + s0 + yy) * vstride + h * NDH + d0 + x];
  __syncthreads();
  for (int yy = threadIdx.y; yy < 32; yy += 8)
    Vt[((size_t)bh * NDH + d0 + yy) * NS + s0 + x] = t[x][yy];
}

// ---------------- small f32 copy (bias packing) ----------------
__global__ void copy_f32(const float* __restrict__ s, float* __restrict__ d, int n) {
  int i = blockIdx.x * 256 + threadIdx.x;
  if (i < n) d[i] = s[i];
}

// ---------------- GEMM: C[M,N] = A[M,K](bf16) * Bt[N,K]^T(bf16) (+bias, +res, relu) ----------------
// 128x128 tile, 4 waves (2x2), 4x4 16x16x32 frags per wave, BK=32, global_load_lds staging.
template<int OUTF32, int RELU>
__global__ __launch_bounds__(256, 2)
void gemm_bt(const u16* __restrict__ A, const u16* __restrict__ Bt,
             const float* __restrict__ bias, const float* __restrict__ res,
             float* __restrict__ outF, u16* __restrict__ outB,
             int M, int N, int K)
{
  __shared__ u16 lA[128 * 32];
  __shared__ u16 lB[128 * 32];
  int tid = threadIdx.x;
  int wid = tid >> 6, lane = tid & 63;
  int lr = lane & 15, lk = lane >> 4;
  int wm = wid >> 1, wn = wid & 1;
  int rowBlk = blockIdx.y * 128, colBlk = blockIdx.x * 128;

  f32x4 acc[4][4];
#pragma unroll
  for (int i = 0; i < 4; i++)
#pragma unroll
    for (int j = 0; j < 4; j++) acc[i][j] = (f32x4){0.f, 0.f, 0.f, 0.f};

  const u16* gA = A + (size_t)(rowBlk + wid * 32 + (lane >> 2)) * K + (lane & 3) * 8;
  const u16* gB = Bt + (size_t)(colBlk + wid * 32 + (lane >> 2)) * K + (lane & 3) * 8;
  u16* lAw = lA + wid * 1024;
  u16* lBw = lB + wid * 1024;

  for (int kk = 0; kk < K; kk += 32) {
    __syncthreads();
    gload_lds16(gA + kk, lAw);
    gload_lds16(gA + kk + (size_t)16 * K, lAw + 512);
    gload_lds16(gB + kk, lBw);
    gload_lds16(gB + kk + (size_t)16 * K, lBw + 512);
    asm volatile("s_waitcnt vmcnt(0)" ::: "memory");
    __syncthreads();

    bf16x8 af[4], bf[4];
#pragma unroll
    for (int fm = 0; fm < 4; fm++)
      af[fm] = ldfrag(lA + (wm * 64 + fm * 16 + lr) * 32 + lk * 8);
#pragma unroll
    for (int fn = 0; fn < 4; fn++)
      bf[fn] = ldfrag(lB + (wn * 64 + fn * 16 + lr) * 32 + lk * 8);
#pragma unroll
    for (int fm = 0; fm < 4; fm++)
#pragma unroll
      for (int fn = 0; fn < 4; fn++)
        acc[fm][fn] = mfma16(af[fm], bf[fn], acc[fm][fn]);
  }

  int orow = rowBlk + wm * 64;
  int ocol = colBlk + wn * 64;
#pragma unroll
  for (int fn = 0; fn < 4; fn++) {
    int c = ocol + fn * 16 + lr;
    float bv = bias[c];
#pragma unroll
    for (int fm = 0; fm < 4; fm++) {
      int r0 = orow + fm * 16 + lk * 4;
#pragma unroll
      for (int j = 0; j < 4; j++) {
        float v = acc[fm][fn][j] + bv;
        if (OUTF32) v += res[(size_t)(r0 + j) * N + c];
        if (RELU) v = fmaxf(v, 0.f);
        if (OUTF32) outF[(size_t)(r0 + j) * N + c] = v;
        else        outB[(size_t)(r0 + j) * N + c] = f2bf(v);
      }
    }
  }
}

// ---------------- flash attention (double-buffered, counted vmcnt, raw barriers) ----------------
// grid 512 = 16 bh * 32 qtiles; 4 waves, each wave: 16 q-rows x DH=256.
// K tile: [32][256] with XOR granule swizzle (global-source side).
// V tile: [g=4][d=256][8] with chunk XOR (lk<<1) swizzle -> 2-way banks on read.
template<int CAUSAL>
__global__ __launch_bounds__(256, 2)
void attn_kernel(const u16* __restrict__ Qp, int qstride,
                 const u16* __restrict__ Kp, int kstride,
                 const u16* __restrict__ Vt, u16* __restrict__ O)
{
  int bidx = blockIdx.x;
  int bh = bidx & (NB * NH - 1);
  int qt = (NS / 64 - 1) - (bidx >> 4);
  int b = bh >> 2, h = bh & (NH - 1);
  int tid = threadIdx.x, wid = tid >> 6, lane = tid & 63;
  int lr = lane & 15, lk = lane >> 4;

  __shared__ u16 lK[2][32 * 256];
  __shared__ u16 lV[2][32 * 256];
  __shared__ u16 lP[4][16 * 32];

  const u16* qbase = Qp + (size_t)(b * NS + qt * 64 + wid * 16 + lr) * qstride + h * NDH;
  bf16x8 qf[8];
#pragma unroll
  for (int k8 = 0; k8 < 8; k8++) qf[k8] = ldfrag(qbase + k8 * 32 + lk * 8);

  f32x4 oacc[16];
#pragma unroll
  for (int dc = 0; dc < 16; dc++) oacc[dc] = (f32x4){0.f, 0.f, 0.f, 0.f};
  float m[4] = {-1e30f, -1e30f, -1e30f, -1e30f};
  float l[4] = {0.f, 0.f, 0.f, 0.f};

  int nkt = CAUSAL ? (2 * qt + 2) : (NS / 32);
  constexpr float SC = 1.0f / NDH;

  const u16* kbase = Kp + (size_t)(b * NS) * kstride + h * NDH;
  const u16* vbase = Vt + (size_t)bh * NDH * NS;

  auto stage = [&](int kt, int buf) {
#pragma unroll
    for (int i = 0; i < 4; i++) {
      int cc = wid * 4 + i;
      int krow = 2 * cc + (lane >> 5);
      int kslot = (lane & 31) ^ (krow & 7);
      gload_lds16(kbase + (size_t)(kt * 32 + krow) * kstride + kslot * 8,
                  &lK[buf][cc * 512]);
      int u = cc * 64 + lane;
      int usw = u ^ (((u >> 8) & 3) << 1);
      int vg = usw >> 8, vd = usw & 255;
      gload_lds16(vbase + (size_t)vd * NS + kt * 32 + vg * 8,
                  &lV[buf][cc * 512]);
    }
  };

  stage(0, 0);

  int lrx = (lr ^ (lk << 1)) * 8;   // swizzled V chunk within 16-slot group
  u16* myP = &lP[wid][0];

  for (int kt = 0; kt < nkt; kt++) {
    const u16* bK = lK[kt & 1];
    const u16* bV = lV[kt & 1];
    if (kt + 1 < nkt) {
      stage(kt + 1, (kt + 1) & 1);
      asm volatile("s_waitcnt vmcnt(8)" ::: "memory");
    } else {
      asm volatile("s_waitcnt vmcnt(0)" ::: "memory");
    }
    __builtin_amdgcn_s_barrier();

    // QK^T
    f32x4 sf0 = (f32x4){0.f, 0.f, 0.f, 0.f};
    f32x4 sf1 = (f32x4){0.f, 0.f, 0.f, 0.f};
#pragma unroll
    for (int k8 = 0; k8 < 8; k8++) {
      int ps = ((k8 * 4 + lk) ^ (lr & 7)) * 8;
      bf16x8 kf0 = ldfrag(bK + lr * 256 + ps);
      bf16x8 kf1 = ldfrag(bK + (16 + lr) * 256 + ps);
      sf0 = mfma16(qf[k8], kf0, sf0);
      sf1 = mfma16(qf[k8], kf1, sf1);
    }

    bool domask = CAUSAL && (kt * 32 + 31 > qt * 64 + wid * 16);
    float tmax[4];
#pragma unroll
    for (int j = 0; j < 4; j++) {
      float a0 = sf0[j] * SC, a1 = sf1[j] * SC;
      if (domask) {
        int q = qt * 64 + wid * 16 + lk * 4 + j;
        if (kt * 32 + lr > q)      a0 = -1e30f;
        if (kt * 32 + 16 + lr > q) a1 = -1e30f;
      }
      sf0[j] = a0; sf1[j] = a1;
      tmax[j] = fmaxf(a0, a1);
    }
#pragma unroll
    for (int j = 0; j < 4; j++) {
      tmax[j] = fmaxf(tmax[j], __shfl_xor(tmax[j], 1));
      tmax[j] = fmaxf(tmax[j], __shfl_xor(tmax[j], 2));
      tmax[j] = fmaxf(tmax[j], __shfl_xor(tmax[j], 4));
      tmax[j] = fmaxf(tmax[j], __shfl_xor(tmax[j], 8));
    }

    float need = tmax[0] - m[0];
    need = fmaxf(need, tmax[1] - m[1]);
    need = fmaxf(need, tmax[2] - m[2]);
    need = fmaxf(need, tmax[3] - m[3]);

    float psum[4];
    if (__all(need <= 5.0f)) {
      // defer-max: keep old m, no rescale (p bounded by e^5)
#pragma unroll
      for (int j = 0; j < 4; j++) {
        float p0 = __expf(sf0[j] - m[j]);
        float p1 = __expf(sf1[j] - m[j]);
        psum[j] = p0 + p1;
        myP[(lk * 4 + j) * 32 + lr]      = f2bf(p0);
        myP[(lk * 4 + j) * 32 + 16 + lr] = f2bf(p1);
      }
    } else {
      float resc[4];
#pragma unroll
      for (int j = 0; j < 4; j++) {
        float mn = fmaxf(m[j], tmax[j]);
        resc[j] = __expf(m[j] - mn);
        m[j] = mn;
        float p0 = __expf(sf0[j] - mn);
        float p1 = __expf(sf1[j] - mn);
        psum[j] = p0 + p1;
        l[j] *= resc[j];
        myP[(lk * 4 + j) * 32 + lr]      = f2bf(p0);
        myP[(lk * 4 + j) * 32 + 16 + lr] = f2bf(p1);
      }
#pragma unroll
      for (int dc = 0; dc < 16; dc++) {
        f32x4 t = oacc[dc];
        t[0] *= resc[0]; t[1] *= resc[1]; t[2] *= resc[2]; t[3] *= resc[3];
        oacc[dc] = t;
      }
    }
#pragma unroll
    for (int j = 0; j < 4; j++) {
      psum[j] += __shfl_xor(psum[j], 1);
      psum[j] += __shfl_xor(psum[j], 2);
      psum[j] += __shfl_xor(psum[j], 4);
      psum[j] += __shfl_xor(psum[j], 8);
      l[j] += psum[j];
    }

    asm volatile("s_waitcnt lgkmcnt(0)" ::: "memory");
    bf16x8 pf = ldfrag(myP + lr * 32 + lk * 8);
#pragma unroll
    for (int dc = 0; dc < 16; dc++) {
      bf16x8 vf = ldfrag(bV + lk * 2048 + dc * 128 + lrx);
      oacc[dc] = mfma16(pf, vf, oacc[dc]);
    }
    __builtin_amdgcn_s_barrier();
  }

  float inv[4];
#pragma unroll
  for (int j = 0; j < 4; j++) inv[j] = 1.f / l[j];
#pragma unroll
  for (int dc = 0; dc < 16; dc++) {
#pragma unroll
    for (int j = 0; j < 4; j++) {
      size_t row = (size_t)(b * NS + qt * 64 + wid * 16 + lk * 4 + j);
      O[row * NE + h * NDH + dc * 16 + lr] = f2bf(oacc[dc][j] * inv[j]);
    }
  }
}

// ---------------- LayerNorm (eps=1e-3), optional relu, optional bf16 copy ----------------
template<int RELU, int WBF>
__global__ __launch_bounds__(256)
void ln_kernel(const float* __restrict__ x, const float* __restrict__ g,
               const float* __restrict__ bb, float* __restrict__ outF,
               u16* __restrict__ outB)
{
  int row = blockIdx.x, tid = threadIdx.x;
  float4 v = ((const float4*)(x + (size_t)row * NE))[tid];
  float s = v.x + v.y + v.z + v.w;
  float s2 = v.x * v.x + v.y * v.y + v.z * v.z + v.w * v.w;
#pragma unroll
  for (int off = 32; off; off >>= 1) {
    s += __shfl_xor(s, off);
    s2 += __shfl_xor(s2, off);
  }
  __shared__ float red[8];
  int wid = tid >> 6, lane = tid & 63;
  if (lane == 0) { red[wid] = s; red[4 + wid] = s2; }
  __syncthreads();
  s = red[0] + red[1] + red[2] + red[3];
  s2 = red[4] + red[5] + red[6] + red[7];
  float mean = s * (1.f / NE);
  float var = s2 * (1.f / NE) - mean * mean;
  float rstd = rsqrtf(var + 1e-3f);
  float4 gg = ((const float4*)g)[tid];
  float4 bv = ((const float4*)bb)[tid];
  float4 o;
  o.x = (v.x - mean) * rstd * gg.x + bv.x;
  o.y = (v.y - mean) * rstd * gg.y + bv.y;
  o.z = (v.z - mean) * rstd * gg.z + bv.z;
  o.w = (v.w - mean) * rstd * gg.w + bv.w;
  if (RELU) {
    o.x = fmaxf(o.x, 0.f); o.y = fmaxf(o.y, 0.f);
    o.z = fmaxf(o.z, 0.f); o.w = fmaxf(o.w, 0.f);
  }
  ((float4*)(outF + (size_t)row * NE))[tid] = o;
  if (WBF) {
    ushort4 ob;
    ob.x = f2bf(o.x); ob.y = f2bf(o.y); ob.z = f2bf(o.z); ob.w = f2bf(o.w);
    ((ushort4*)(outB + (size_t)row * NE))[tid] = ob;
  }
}

// ---------------- workspace layout (bytes) ----------------
constexpr size_t OFF_X    = 0;                       // 16 MB: Xbf -> O1 -> Ctxbf -> O2
constexpr size_t OFF_W    = OFF_X + 16777216;        // 32 MB packed weights
constexpr size_t OFF_BIAS = OFF_W + 33554432;        // packed biases
constexpr size_t OFF_QKV  = OFF_BIAS + 32768;        // 48 MB QKV1 / (KV2 + Q2) / MID(64MB spans into VT)
constexpr size_t OFF_VT   = OFF_QKV + 50331648;      // 16 MB Vt
constexpr size_t OFF_T0   = OFF_VT + 16777216;       // 32 MB f32 scratch (pre-LN)
constexpr size_t OFF_A    = OFF_T0 + 33554432;       // 32 MB f32 a / c
constexpr size_t OFF_ABF  = OFF_A + 33554432;        // 16 MB bf16 a / c

extern "C" void kernel_launch(void* const* d_in, const int* in_sizes, int n_in,
                              void* d_out, int out_size, void* d_ws, size_t ws_size,
                              hipStream_t stream) {
  (void)in_sizes; (void)n_in; (void)out_size; (void)ws_size;
  const float* inp = (const float*)d_in[0];
  const float* ctx = (const float*)d_in[1];
  const float* Wk1 = (const float*)d_in[2];  const float* bk1 = (const float*)d_in[3];
  const float* Wq1 = (const float*)d_in[4];  const float* bq1 = (const float*)d_in[5];
  const float* Wv1 = (const float*)d_in[6];  const float* bv1 = (const float*)d_in[7];
  const float* Wo1 = (const float*)d_in[8];  const float* bo1 = (const float*)d_in[9];
  const float* Wk2 = (const float*)d_in[10]; const float* bk2 = (const float*)d_in[11];
  const float* Wq2 = (const float*)d_in[12]; const float* bq2 = (const float*)d_in[13];
  const float* Wv2 = (const float*)d_in[14]; const float* bv2 = (const float*)d_in[15];
  const float* Wo2 = (const float*)d_in[16]; const float* bo2 = (const float*)d_in[17];
  const float* lng = (const float*)d_in[18]; const float* lnb = (const float*)d_in[19];
  const float* W1  = (const float*)d_in[20]; const float* b1  = (const float*)d_in[21];
  const float* W2  = (const float*)d_in[22]; const float* b2  = (const float*)d_in[23];
  float* out = (float*)d_out;
  char* ws = (char*)d_ws;

  u16* XBF    = (u16*)(ws + OFF_X);        // also ctx-bf16 and attention-O buffer
  u16* WQKV1T = (u16*)(ws + OFF_W);        // rows [K|Q|V] x 1024
  u16* WKV2T  = WQKV1T + 3072 * 1024;      // rows [K|V] x 1024
  u16* WQ2T   = WKV2T + 2048 * 1024;
  u16* WO1T   = WQ2T + 1024 * 1024;
  u16* WO2T   = WO1T + 1024 * 1024;
  u16* W1T    = WO2T + 1024 * 1024;        // [4096][1024]
  u16* W2T    = W1T + 4096 * 1024;         // [1024][4096]
  float* BQKV1 = (float*)(ws + OFF_BIAS);  // 3072
  float* BKV2  = BQKV1 + 3072;             // 2048
  u16* QKV  = (u16*)(ws + OFF_QKV);        // [8192][3072] (self) / [8192][2048] KV2
  u16* Q2   = QKV + 8192 * 2048;           // [8192][1024]
  u16* VT   = (u16*)(ws + OFF_VT);         // [16][256][2048]
  u16* MID  = QKV;                         // [8192][4096] (aliases QKV+VT, both dead)
  float* T0 = (float*)(ws + OFF_T0);
  float* Af = (float*)(ws + OFF_A);
  u16* ABF  = (u16*)(ws + OFF_ABF);
  u16* Obuf = XBF;

  dim3 tb(32, 8);

  // input cast + weight/bias packing
  cast_f32_bf16<<<8192, 256, 0, stream>>>(inp, XBF, NR * NE / 4);
  transpose_cast<<<dim3(8, 32, 4), tb, 0, stream>>>(Wk1, WQKV1T,               NE, NDH);
  transpose_cast<<<dim3(8, 32, 4), tb, 0, stream>>>(Wq1, WQKV1T + 1024 * 1024, NE, NDH);
  transpose_cast<<<dim3(8, 32, 4), tb, 0, stream>>>(Wv1, WQKV1T + 2048 * 1024, NE, NDH);
  transpose_cast<<<dim3(32, 32, 1), tb, 0, stream>>>(Wo1, WO1T, NE, NE);
  transpose_cast<<<dim3(8, 32, 4), tb, 0, stream>>>(Wk2, WKV2T,               NE, NDH);
  transpose_cast<<<dim3(8, 32, 4), tb, 0, stream>>>(Wv2, WKV2T + 1024 * 1024, NE, NDH);
  transpose_cast<<<dim3(8, 32, 4), tb, 0, stream>>>(Wq2, WQ2T, NE, NDH);
  transpose_cast<<<dim3(32, 32, 1), tb, 0, stream>>>(Wo2, WO2T, NE, NE);
  transpose_cast<<<dim3(128, 32, 1), tb, 0, stream>>>(W1, W1T, NE, NF);
  transpose_cast<<<dim3(32, 128, 1), tb, 0, stream>>>(W2, W2T, NF, NE);
  copy_f32<<<4, 256, 0, stream>>>(bk1, BQKV1, 1024);
  copy_f32<<<4, 256, 0, stream>>>(bq1, BQKV1 + 1024, 1024);
  copy_f32<<<4, 256, 0, stream>>>(bv1, BQKV1 + 2048, 1024);
  copy_f32<<<4, 256, 0, stream>>>(bk2, BKV2, 1024);
  copy_f32<<<4, 256, 0, stream>>>(bv2, BKV2 + 1024, 1024);

  // ---- self-attention block ----
  gemm_bt<0, 0><<<dim3(24, 64), 256, 0, stream>>>(XBF, WQKV1T, BQKV1, nullptr,
                                                  nullptr, QKV, NR, 3072, NE);
  transpose_v<<<dim3(64, 8, 16), tb, 0, stream>>>(QKV + 2048, 3072, VT);
  attn_kernel<1><<<512, 256, 0, stream>>>(QKV + 1024, 3072, QKV, 3072, VT, Obuf);
  gemm_bt<1, 0><<<dim3(8, 64), 256, 0, stream>>>(Obuf, WO1T, bo1, inp,
                                                 T0, nullptr, NR, NE, NE);
  ln_kernel<0, 1><<<NR, 256, 0, stream>>>(T0, lng, lnb, Af, ABF);

  // ---- cross-attention block ----
  cast_f32_bf16<<<8192, 256, 0, stream>>>(ctx, XBF, NR * NE / 4);
  gemm_bt<0, 0><<<dim3(16, 64), 256, 0, stream>>>(XBF, WKV2T, BKV2, nullptr,
                                                  nullptr, QKV, NR, 2048, NE);
  gemm_bt<0, 0><<<dim3(8, 64), 256, 0, stream>>>(ABF, WQ2T, bq2, nullptr,
                                                 nullptr, Q2, NR, NE, NE);
  transpose_v<<<dim3(64, 8, 16), tb, 0, stream>>>(QKV + 1024, 2048, VT);
  attn_kernel<0><<<512, 256, 0, stream>>>(Q2, 1024, QKV, 2048, VT, Obuf);
  gemm_bt<1, 0><<<dim3(8, 64), 256, 0, stream>>>(Obuf, WO2T, bo2, Af,
                                                 T0, nullptr, NR, NE, NE);
  ln_kernel<0, 1><<<NR, 256, 0, stream>>>(T0, lng, lnb, Af, ABF);

  // ---- FFN ----
  gemm_bt<0, 1><<<dim3(32, 64), 256, 0, stream>>>(ABF, W1T, b1, nullptr,
                                                  nullptr, MID, NR, NF, NE);
  gemm_bt<1, 0><<<dim3(8, 64), 256, 0, stream>>>(MID, W2T, b2, Af,
                                                 T0, nullptr, NR, NE, NF);
  ln_kernel<1, 0><<<NR, 256, 0, stream>>>(T0, lng, lnb, out, nullptr);
}